// Round 21
// baseline (297.416 us; speedup 1.0000x reference)
//
#include <hip/hip_runtime.h>
#include <cstdint>
#include <cstddef>

#define LOG2E 1.4426950408889634f

constexpr int Dm  = 192;
constexpr int DEe = 96;

typedef unsigned short u16;
typedef __attribute__((ext_vector_type(8))) short short8v;
typedef __attribute__((ext_vector_type(4))) float f32x4;

__device__ __forceinline__ u16 f2bf(float f) {
    uint32_t u = __builtin_bit_cast(uint32_t, f);
    uint32_t r = (u + 0x7FFF + ((u >> 16) & 1)) >> 16;
    return (u16)r;
}
__device__ __forceinline__ float bf2f(u16 h) {
    uint32_t u = ((uint32_t)h) << 16;
    return __builtin_bit_cast(float, u);
}
// packed f32x2 -> bf16x2 (RNE), 1 VALU op for 2 values
__device__ __forceinline__ uint32_t cvtpk_bf16(float lo, float hi) {
    uint32_t r;
    asm("v_cvt_pk_bf16_f32 %0, %1, %2" : "=v"(r) : "v"(lo), "v"(hi));
    return r;
}

// ---------------------------------------------------------------- utilities
__global__ __launch_bounds__(1024) void scan_kernel(const int* __restrict__ deg, int N,
                                                    int* __restrict__ offs) {
    __shared__ int sp[1024];
    int t = threadIdx.x;
    int per = (N + 1023) >> 10;
    int base = t * per;
    int sum = 0;
    for (int i = 0; i < per; ++i) {
        int idx = base + i;
        if (idx < N) sum += deg[idx];
    }
    sp[t] = sum;
    __syncthreads();
    for (int off = 1; off < 1024; off <<= 1) {
        int v = (t >= off) ? sp[t - off] : 0;
        __syncthreads();
        sp[t] += v;
        __syncthreads();
    }
    int run = sp[t] - sum;
    for (int i = 0; i < per; ++i) {
        int idx = base + i;
        if (idx < N) { offs[idx] = run; run += deg[idx]; }
    }
    if (t == 1023) offs[N] = sp[1023];
}

// ---------------- prepA: count_deg | xconv | ef->bf16 | prep_w | Wet (merged)
__global__ __launch_bounds__(256) void prepA(
    const int* __restrict__ ei, int E,
    const float* __restrict__ x, int n4, u16* __restrict__ xb,
    const float* __restrict__ ef, int nef4, u16* __restrict__ efb,
    const float* __restrict__ Wq, const float* __restrict__ Wk,
    const float* __restrict__ Wv, const float* __restrict__ Wo,
    const float* __restrict__ Wg, const float* __restrict__ Wf1,
    const float* __restrict__ Wf2, const float* __restrict__ We,
    u16* __restrict__ Wqkvt, u16* __restrict__ Wot,
    u16* __restrict__ Wgt, u16* __restrict__ Wf1t, u16* __restrict__ Wf2t,
    u16* __restrict__ Wet,
    int* __restrict__ deg)
{
    int i = blockIdx.x * 256 + threadIdx.x;
    if (i < E) {
        atomicAdd(&deg[ei[E + i]], 1);
        return;
    }
    i -= E;
    if (i < n4) {                          // xconv: float4 -> bf16x4
        float4 v = ((const float4*)x)[i];
        uint32_t p0 = cvtpk_bf16(v.x, v.y);
        uint32_t p1 = cvtpk_bf16(v.z, v.w);
        ushort4 o;
        o.x = (u16)(p0 & 0xffff); o.y = (u16)(p0 >> 16);
        o.z = (u16)(p1 & 0xffff); o.w = (u16)(p1 >> 16);
        ((ushort4*)xb)[i] = o;
        return;
    }
    i -= n4;
    if (i < nef4) {                        // ef conv: float4 -> bf16x4 (same RNE)
        float4 v = ((const float4*)ef)[i];
        uint32_t p0 = cvtpk_bf16(v.x, v.y);
        uint32_t p1 = cvtpk_bf16(v.z, v.w);
        ushort4 o;
        o.x = (u16)(p0 & 0xffff); o.y = (u16)(p0 >> 16);
        o.z = (u16)(p1 & 0xffff); o.w = (u16)(p1 >> 16);
        ((ushort4*)efb)[i] = o;
        return;
    }
    int idx = i - nef4;
    if (idx < 110592) {                    // QKV: [576][192]
        int n = idx / 192, k = idx % 192;
        const float* W = n < 192 ? Wq : (n < 384 ? Wk : Wv);
        Wqkvt[idx] = f2bf(W[(size_t)k * 192 + (n % 192)]);
    } else if (idx < 147456) {             // Wo: [192][192]
        int j = idx - 110592;
        int n = j / 192, k = j % 192;
        Wot[j] = f2bf(Wo[(size_t)k * 192 + n]);
    } else if (idx < 221184) {             // Wg: [192][384]
        int j = idx - 147456;
        int n = j / 384, k = j % 384;
        Wgt[j] = f2bf(Wg[(size_t)k * 192 + n]);
    } else if (idx < 294912) {             // Wf1: [384][192]
        int j = idx - 221184;
        int n = j / 192, k = j % 192;
        Wf1t[j] = f2bf(Wf1[(size_t)k * 384 + n]);
    } else if (idx < 368640) {             // Wf2: [192][384]
        int j = idx - 294912;
        int n = j / 384, k = j % 384;
        Wf2t[j] = f2bf(Wf2[(size_t)k * 192 + n]);
    } else if (idx < 370176) {             // Wet: [16][96], log2e-scaled, rows 8..15 = 0
        int j = idx - 368640;
        int n = j / 96, k = j % 96;
        Wet[j] = (n < 8) ? f2bf(We[(size_t)k * 8 + n] * LOG2E) : (u16)0;
    }
}

// ---------------- phaseC: edge MFMA blocks [0,EB) | qkv BM=64 blocks [EB,EB+QB)
// edge role: es = (efb @ We)*log2e via 16x16x32 MFMA; A-fragments loaded
// DIRECTLY as bf16 short8v (16B) from efb -> half the gather bytes of r12,
// then CSR scatter of es + src.
__global__ __launch_bounds__(256) void phaseC(
    int EB,
    // edge role
    const int* __restrict__ ei, int E,
    const u16* __restrict__ efb, const u16* __restrict__ Wet,
    const int* __restrict__ offs, int* __restrict__ cur,
    float* __restrict__ scb, int* __restrict__ sbuf,
    // qkv role
    const u16* __restrict__ xb, int M, int gm64,
    const u16* __restrict__ Wt, u16* __restrict__ qkvb)
{
    int bid = blockIdx.x;
    int tid = threadIdx.x;
    int w = tid >> 6, lane = tid & 63;
    int c16 = lane & 15, hi2 = lane >> 4, kof = hi2 * 8;

    if (bid < EB) {
        // ---------------- edge projection + scatter, 64 edges per wave
        int ebase = bid * 256 + w * 64;
        if (ebase >= E) return;

        // B fragments: Wet[c16][ks*32 + kof .. +8] (rows 8..15 are zero)
        short8v bfr[3];
        #pragma unroll
        for (int ks = 0; ks < 3; ++ks)
            bfr[ks] = *(const short8v*)(Wet + (size_t)c16 * 96 + ks * 32 + kof);

        #pragma unroll 1
        for (int mt = 0; mt < 4; ++mt) {
            int er = ebase + mt * 16 + c16;
            if (er > E - 1) er = E - 1;
            const u16* efr = efb + (size_t)er * 96;

            f32x4 acc = (f32x4)(0.f);
            #pragma unroll
            for (int ks = 0; ks < 3; ++ks) {
                short8v af = *(const short8v*)(efr + ks * 32 + kof);
                acc = __builtin_amdgcn_mfma_f32_16x16x32_bf16(af, bfr[ks], acc, 0, 0, 0);
            }

            // scatter: D row = hi2*4+reg (edge), col = c16 (head, <8 valid)
            int erow0 = ebase + mt * 16 + hi2 * 4;
            int posr[4];
            if (c16 == 0) {
                #pragma unroll
                for (int reg = 0; reg < 4; ++reg) {
                    int e = erow0 + reg;
                    if (e < E) {
                        int dst = ei[E + e];
                        posr[reg] = offs[dst] + atomicAdd(&cur[dst], 1);
                        sbuf[posr[reg]] = ei[e];
                    }
                }
            }
            #pragma unroll
            for (int reg = 0; reg < 4; ++reg) {
                int e = erow0 + reg;
                int p = __shfl(posr[reg], lane & 48, 64);
                if (e < E && c16 < 8)
                    scb[(size_t)p * 8 + c16] = acc[reg];
            }
        }
        return;
    }

    // ---------------- qkv: zero-LDS fragment GEMM, BM=64, 4 waves
    int qb = bid - EB;
    int m0 = (qb % gm64) * 64, n0 = (qb / gm64) * 192;

    int rcm[4];
    #pragma unroll
    for (int mr = 0; mr < 4; ++mr) {
        int r = m0 + mr * 16 + c16;
        rcm[mr] = r < M ? r : M - 1;
    }

    f32x4 acc[4][3];
    #pragma unroll
    for (int mr = 0; mr < 4; ++mr)
        #pragma unroll
        for (int nr = 0; nr < 3; ++nr) acc[mr][nr] = (f32x4)(0.f);

    #pragma unroll 1
    for (int ks = 0; ks < 6; ++ks) {
        short8v af[4], bfr[3];
        #pragma unroll
        for (int mr = 0; mr < 4; ++mr)
            af[mr] = *(const short8v*)(xb + (size_t)rcm[mr] * 192 + ks * 32 + kof);
        #pragma unroll
        for (int nr = 0; nr < 3; ++nr)
            bfr[nr] = *(const short8v*)(Wt + (size_t)(n0 + w * 48 + nr * 16 + c16) * 192 + ks * 32 + kof);
        #pragma unroll
        for (int mr = 0; mr < 4; ++mr)
            #pragma unroll
            for (int nr = 0; nr < 3; ++nr)
                acc[mr][nr] = __builtin_amdgcn_mfma_f32_16x16x32_bf16(
                    af[mr], bfr[nr], acc[mr][nr], 0, 0, 0);
    }

    #pragma unroll
    for (int mr = 0; mr < 4; ++mr)
        #pragma unroll
        for (int nr = 0; nr < 3; ++nr) {
            uint32_t p0 = cvtpk_bf16(acc[mr][nr][0], acc[mr][nr][1]);
            uint32_t p1 = cvtpk_bf16(acc[mr][nr][2], acc[mr][nr][3]);
            int r0 = m0 + mr * 16 + hi2 * 4;
            int col = n0 + w * 48 + nr * 16 + c16;
            if (r0     < M) qkvb[(size_t)(r0    ) * 576 + col] = (u16)(p0 & 0xffff);
            if (r0 + 1 < M) qkvb[(size_t)(r0 + 1) * 576 + col] = (u16)(p0 >> 16);
            if (r0 + 2 < M) qkvb[(size_t)(r0 + 2) * 576 + col] = (u16)(p1 & 0xffff);
            if (r0 + 3 < M) qkvb[(size_t)(r0 + 3) * 576 + col] = (u16)(p1 >> 16);
        }
}

// ---------------------------------------- fused score + softmax + PV per node
// pair-wise, 2-pair-deep software pipeline
__global__ __launch_bounds__(256) void agg_fused(
    const u16* __restrict__ qkv, const float* __restrict__ scb,
    const int* __restrict__ sbuf, const int* __restrict__ offs,
    int N, u16* __restrict__ aggb)
{
    int node = blockIdx.x * 4 + (threadIdx.x >> 6);
    if (node >= N) return;
    int lane = threadIdx.x & 63;
    int h = lane >> 3;
    int di = (3 * lane) >> 1;
    int odd = lane & 1;

    int beg = offs[node], end = offs[node + 1];
    u16* og = aggb + (size_t)node * Dm;
    int b0 = 3 * lane;
    if (beg >= end) {
        og[b0] = 0; og[b0 + 1] = 0; og[b0 + 2] = 0;
        return;
    }

    const uint32_t* qrow = (const uint32_t*)(qkv + (size_t)node * 576);
    uint32_t qd0 = qrow[di], qd1 = qrow[di + 1];
    float q0, q1, q2;
    if (!odd) { q0 = bf2f(qd0 & 0xffff); q1 = bf2f(qd0 >> 16); q2 = bf2f(qd1 & 0xffff); }
    else      { q0 = bf2f(qd0 >> 16);    q1 = bf2f(qd1 & 0xffff); q2 = bf2f(qd1 >> 16); }

    auto clampi = [&](int i) { return i < end ? i : end - 1; };

    float den = 0.f, a0 = 0.f, a1 = 0.f, a2 = 0.f;

    uint32_t ck[2][2], cv[2][2]; float cep[2];
    uint32_t nk[2][2], nv[2][2]; float nep[2];
    int s0, s1;

    {
        int p00 = clampi(beg),     p01 = clampi(beg + 1);
        int p10 = clampi(beg + 2), p11 = clampi(beg + 3);
        int sA = sbuf[p00], sB = sbuf[p01], sC = sbuf[p10], sD = sbuf[p11];
        const uint32_t* r;
        r = (const uint32_t*)(qkv + (size_t)sA * 576 + 192);
        ck[0][0] = r[di]; ck[0][1] = r[di + 1];
        r = (const uint32_t*)(qkv + (size_t)sA * 576 + 384);
        cv[0][0] = r[di]; cv[0][1] = r[di + 1];
        r = (const uint32_t*)(qkv + (size_t)sB * 576 + 192);
        ck[1][0] = r[di]; ck[1][1] = r[di + 1];
        r = (const uint32_t*)(qkv + (size_t)sB * 576 + 384);
        cv[1][0] = r[di]; cv[1][1] = r[di + 1];
        r = (const uint32_t*)(qkv + (size_t)sC * 576 + 192);
        nk[0][0] = r[di]; nk[0][1] = r[di + 1];
        r = (const uint32_t*)(qkv + (size_t)sC * 576 + 384);
        nv[0][0] = r[di]; nv[0][1] = r[di + 1];
        r = (const uint32_t*)(qkv + (size_t)sD * 576 + 192);
        nk[1][0] = r[di]; nk[1][1] = r[di + 1];
        r = (const uint32_t*)(qkv + (size_t)sD * 576 + 384);
        nv[1][0] = r[di]; nv[1][1] = r[di + 1];
        cep[0] = scb[(size_t)p00 * 8 + h]; cep[1] = scb[(size_t)p01 * 8 + h];
        nep[0] = scb[(size_t)p10 * 8 + h]; nep[1] = scb[(size_t)p11 * 8 + h];
        s0 = sbuf[clampi(beg + 4)]; s1 = sbuf[clampi(beg + 5)];
    }

    for (int idx = beg; idx < end; idx += 2) {
        #pragma unroll
        for (int j = 0; j < 2; ++j) {
            float k0, k1, k2, v0, v1, v2;
            uint32_t kd0 = ck[j][0], kd1 = ck[j][1];
            uint32_t vd0 = cv[j][0], vd1 = cv[j][1];
            if (!odd) {
                k0 = bf2f(kd0 & 0xffff); k1 = bf2f(kd0 >> 16); k2 = bf2f(kd1 & 0xffff);
                v0 = bf2f(vd0 & 0xffff); v1 = bf2f(vd0 >> 16); v2 = bf2f(vd1 & 0xffff);
            } else {
                k0 = bf2f(kd0 >> 16); k1 = bf2f(kd1 & 0xffff); k2 = bf2f(kd1 >> 16);
                v0 = bf2f(vd0 >> 16); v1 = bf2f(vd1 & 0xffff); v2 = bf2f(vd1 >> 16);
            }
            float pd = q0 * k0 + q1 * k1 + q2 * k2;
            pd += __shfl_xor(pd, 1, 64);
            pd += __shfl_xor(pd, 2, 64);
            pd += __shfl_xor(pd, 4, 64);
            float p = exp2f(pd * 0.2944885836f + cep[j]);
            if (idx + j < end) {
                den += p;
                a0 += p * v0; a1 += p * v1; a2 += p * v2;
            }
        }
        #pragma unroll
        for (int j = 0; j < 2; ++j) {
            ck[j][0] = nk[j][0]; ck[j][1] = nk[j][1];
            cv[j][0] = nv[j][0]; cv[j][1] = nv[j][1];
            cep[j] = nep[j];
        }
        {
            const uint32_t* r;
            r = (const uint32_t*)(qkv + (size_t)s0 * 576 + 192);
            nk[0][0] = r[di]; nk[0][1] = r[di + 1];
            r = (const uint32_t*)(qkv + (size_t)s0 * 576 + 384);
            nv[0][0] = r[di]; nv[0][1] = r[di + 1];
            r = (const uint32_t*)(qkv + (size_t)s1 * 576 + 192);
            nk[1][0] = r[di]; nk[1][1] = r[di + 1];
            r = (const uint32_t*)(qkv + (size_t)s1 * 576 + 384);
            nv[1][0] = r[di]; nv[1][1] = r[di + 1];
            nep[0] = scb[(size_t)clampi(idx + 4) * 8 + h];
            nep[1] = scb[(size_t)clampi(idx + 5) * 8 + h];
        }
        s0 = sbuf[clampi(idx + 6)]; s1 = sbuf[clampi(idx + 7)];
    }

    float rden = 1.f / (den + 1e-8f);
    og[b0]     = f2bf(a0 * rden);
    og[b0 + 1] = f2bf(a1 * rden);
    og[b0 + 2] = f2bf(a2 * rden);
}

// ---------------------------------------- fused node chain (BM=128, 8 waves)
__global__ __launch_bounds__(512) void chain_fused(
    const u16* __restrict__ aggb, const u16* __restrict__ xb, int M,
    const u16* __restrict__ Wot, const float* __restrict__ bo,
    const u16* __restrict__ Wgt, const float* __restrict__ bg,
    const float* __restrict__ l1s, const float* __restrict__ l1b,
    const u16* __restrict__ Wf1t, const float* __restrict__ bf1,
    const u16* __restrict__ Wf2t, const float* __restrict__ bf2,
    const float* __restrict__ l2s, const float* __restrict__ l2b,
    float* __restrict__ out)
{
    __shared__ __align__(16) short Ybuf[128 * 200];
    __shared__ __align__(16) short Fbuf[128 * 392];
    __shared__ float red[2][4][128];

    int tid = threadIdx.x;
    int m0 = blockIdx.x * 128;
    int w = tid >> 6, lane = tid & 63;
    int wr = w >> 2, wc = w & 3;
    int c16 = lane & 15, hi2 = lane >> 4, kof = hi2 * 8;
    int rbase = m0 + wr * 64;
    int lbase = wr * 64;

    int rcm[4];
    #pragma unroll
    for (int mr = 0; mr < 4; ++mr) {
        int r = rbase + mr * 16 + c16;
        rcm[mr] = r < M ? r : M - 1;
    }

    // ---- stage0: o = agg @ Wo + bo
    f32x4 oacc[4][3];
    #pragma unroll
    for (int mr = 0; mr < 4; ++mr)
        #pragma unroll
        for (int nr = 0; nr < 3; ++nr) oacc[mr][nr] = (f32x4)(0.f);
    #pragma unroll 1
    for (int ks = 0; ks < 6; ++ks) {
        short8v af[4], bfr[3];
        #pragma unroll
        for (int mr = 0; mr < 4; ++mr)
            af[mr] = *(const short8v*)(aggb + (size_t)rcm[mr] * 192 + ks * 32 + kof);
        #pragma unroll
        for (int nr = 0; nr < 3; ++nr)
            bfr[nr] = *(const short8v*)(Wot + (size_t)(wc * 48 + nr * 16 + c16) * 192 + ks * 32 + kof);
        #pragma unroll
        for (int mr = 0; mr < 4; ++mr)
            #pragma unroll
            for (int nr = 0; nr < 3; ++nr)
                oacc[mr][nr] = __builtin_amdgcn_mfma_f32_16x16x32_bf16(
                    af[mr], bfr[nr], oacc[mr][nr], 0, 0, 0);
    }
    #pragma unroll
    for (int nr = 0; nr < 3; ++nr) {
        int col = wc * 48 + nr * 16 + c16;
        float b = bo[col];
        #pragma unroll
        for (int mr = 0; mr < 4; ++mr) {
            #pragma unroll
            for (int reg = 0; reg < 4; ++reg) oacc[mr][nr][reg] += b;
            uint32_t p0 = cvtpk_bf16(oacc[mr][nr][0], oacc[mr][nr][1]);
            uint32_t p1 = cvtpk_bf16(oacc[mr][nr][2], oacc[mr][nr][3]);
            int row0 = lbase + mr * 16 + hi2 * 4;
            Ybuf[(row0    ) * 200 + col] = (short)(p0 & 0xffff);
            Ybuf[(row0 + 1) * 200 + col] = (short)(p0 >> 16);
            Ybuf[(row0 + 2) * 200 + col] = (short)(p1 & 0xffff);
            Ybuf[(row0 + 3) * 200 + col] = (short)(p1 >> 16);
        }
    }
    __syncthreads();

    // ---- stage1: z = [o,x] @ Wg + bg; gate; LN1 -> y
    f32x4 zacc[4][3];
    #pragma unroll
    for (int mr = 0; mr < 4; ++mr)
        #pragma unroll
        for (int nr = 0; nr < 3; ++nr) zacc[mr][nr] = (f32x4)(0.f);
    #pragma unroll 1
    for (int ks = 0; ks < 6; ++ks) {
        short8v af[4], bfr[3];
        #pragma unroll
        for (int mr = 0; mr < 4; ++mr)
            af[mr] = *(const short8v*)&Ybuf[(lbase + mr * 16 + c16) * 200 + ks * 32 + kof];
        #pragma unroll
        for (int nr = 0; nr < 3; ++nr)
            bfr[nr] = *(const short8v*)(Wgt + (size_t)(wc * 48 + nr * 16 + c16) * 384 + ks * 32 + kof);
        #pragma unroll
        for (int mr = 0; mr < 4; ++mr)
            #pragma unroll
            for (int nr = 0; nr < 3; ++nr)
                zacc[mr][nr] = __builtin_amdgcn_mfma_f32_16x16x32_bf16(
                    af[mr], bfr[nr], zacc[mr][nr], 0, 0, 0);
    }
    #pragma unroll 1
    for (int ks = 0; ks < 6; ++ks) {
        short8v af[4], bfr[3];
        #pragma unroll
        for (int mr = 0; mr < 4; ++mr)
            af[mr] = *(const short8v*)(xb + (size_t)rcm[mr] * 192 + ks * 32 + kof);
        #pragma unroll
        for (int nr = 0; nr < 3; ++nr)
            bfr[nr] = *(const short8v*)(Wgt + (size_t)(wc * 48 + nr * 16 + c16) * 384 + 192 + ks * 32 + kof);
        #pragma unroll
        for (int mr = 0; mr < 4; ++mr)
            #pragma unroll
            for (int nr = 0; nr < 3; ++nr)
                zacc[mr][nr] = __builtin_amdgcn_mfma_f32_16x16x32_bf16(
                    af[mr], bfr[nr], zacc[mr][nr], 0, 0, 0);
    }
    float s1p[4][4], s2p[4][4];
    #pragma unroll
    for (int mr = 0; mr < 4; ++mr)
        #pragma unroll
        for (int reg = 0; reg < 4; ++reg) {
            int gr = rbase + mr * 16 + hi2 * 4 + reg;
            int rcR = gr < M ? gr : M - 1;
            float s1 = 0.f, s2 = 0.f;
            #pragma unroll
            for (int nr = 0; nr < 3; ++nr) {
                int col = wc * 48 + nr * 16 + c16;
                float z = zacc[mr][nr][reg] + bg[col];
                float g = 1.f / (1.f + expf(-z));
                float xv = bf2f(xb[(size_t)rcR * 192 + col]);
                float val = g * oacc[mr][nr][reg] + (1.f - g) * xv;
                zacc[mr][nr][reg] = val;
                s1 += val; s2 += val * val;
            }
            #pragma unroll
            for (int mS = 1; mS < 16; mS <<= 1) {
                s1 += __shfl_xor(s1, mS, 64);
                s2 += __shfl_xor(s2, mS, 64);
            }
            s1p[mr][reg] = s1; s2p[mr][reg] = s2;
        }
    if (c16 == 0) {
        #pragma unroll
        for (int mr = 0; mr < 4; ++mr)
            #pragma unroll
            for (int reg = 0; reg < 4; ++reg) {
                int rowIdx = lbase + mr * 16 + hi2 * 4 + reg;
                red[0][wc][rowIdx] = s1p[mr][reg];
                red[1][wc][rowIdx] = s2p[mr][reg];
            }
    }
    __syncthreads();
    #pragma unroll
    for (int mr = 0; mr < 4; ++mr)
        #pragma unroll
        for (int reg = 0; reg < 4; ++reg) {
            int rowIdx = lbase + mr * 16 + hi2 * 4 + reg;
            float S1 = red[0][0][rowIdx] + red[0][1][rowIdx] + red[0][2][rowIdx] + red[0][3][rowIdx];
            float S2 = red[1][0][rowIdx] + red[1][1][rowIdx] + red[1][2][rowIdx] + red[1][3][rowIdx];
            float mean = S1 * (1.f / 192.f);
            float var  = S2 * (1.f / 192.f) - mean * mean;
            float inv  = rsqrtf(var + 1e-5f);
            #pragma unroll
            for (int nr = 0; nr < 3; ++nr) {
                int col = wc * 48 + nr * 16 + c16;
                float yv = (zacc[mr][nr][reg] - mean) * inv * l1s[col] + l1b[col];
                Ybuf[rowIdx * 200 + col] = (short)f2bf(yv);
            }
        }
    __syncthreads();

    // ---- stage2: t = silu(y @ Wf1 + bf1)
    f32x4 tacc[4][6];
    #pragma unroll
    for (int mr = 0; mr < 4; ++mr)
        #pragma unroll
        for (int nr = 0; nr < 6; ++nr) tacc[mr][nr] = (f32x4)(0.f);
    #pragma unroll 1
    for (int ks = 0; ks < 6; ++ks) {
        short8v af[4], bfr[6];
        #pragma unroll
        for (int mr = 0; mr < 4; ++mr)
            af[mr] = *(const short8v*)&Ybuf[(lbase + mr * 16 + c16) * 200 + ks * 32 + kof];
        #pragma unroll
        for (int nr = 0; nr < 6; ++nr)
            bfr[nr] = *(const short8v*)(Wf1t + (size_t)(wc * 96 + nr * 16 + c16) * 192 + ks * 32 + kof);
        #pragma unroll
        for (int mr = 0; mr < 4; ++mr)
            #pragma unroll
            for (int nr = 0; nr < 6; ++nr)
                tacc[mr][nr] = __builtin_amdgcn_mfma_f32_16x16x32_bf16(
                    af[mr], bfr[nr], tacc[mr][nr], 0, 0, 0);
    }
    #pragma unroll
    for (int nr = 0; nr < 6; ++nr) {
        int col = wc * 96 + nr * 16 + c16;
        float b = bf1[col];
        #pragma unroll
        for (int mr = 0; mr < 4; ++mr) {
            float t0[4];
            #pragma unroll
            for (int reg = 0; reg < 4; ++reg) {
                float z = tacc[mr][nr][reg] + b;
                t0[reg] = z / (1.f + expf(-z));
            }
            uint32_t p0 = cvtpk_bf16(t0[0], t0[1]);
            uint32_t p1 = cvtpk_bf16(t0[2], t0[3]);
            int row0 = lbase + mr * 16 + hi2 * 4;
            Fbuf[(row0    ) * 392 + col] = (short)(p0 & 0xffff);
            Fbuf[(row0 + 1) * 392 + col] = (short)(p0 >> 16);
            Fbuf[(row0 + 2) * 392 + col] = (short)(p1 & 0xffff);
            Fbuf[(row0 + 3) * 392 + col] = (short)(p1 >> 16);
        }
    }
    __syncthreads();

    // ---- stage3: out = LN2(y + t @ Wf2 + bf2)
    f32x4 facc[4][3];
    #pragma unroll
    for (int mr = 0; mr < 4; ++mr)
        #pragma unroll
        for (int nr = 0; nr < 3; ++nr) facc[mr][nr] = (f32x4)(0.f);
    #pragma unroll 1
    for (int ks = 0; ks < 12; ++ks) {
        short8v af[4], bfr[3];
        #pragma unroll
        for (int mr = 0; mr < 4; ++mr)
            af[mr] = *(const short8v*)&Fbuf[(lbase + mr * 16 + c16) * 392 + ks * 32 + kof];
        #pragma unroll
        for (int nr = 0; nr < 3; ++nr)
            bfr[nr] = *(const short8v*)(Wf2t + (size_t)(wc * 48 + nr * 16 + c16) * 384 + ks * 32 + kof);
        #pragma unroll
        for (int mr = 0; mr < 4; ++mr)
            #pragma unroll
            for (int nr = 0; nr < 3; ++nr)
                facc[mr][nr] = __builtin_amdgcn_mfma_f32_16x16x32_bf16(
                    af[mr], bfr[nr], facc[mr][nr], 0, 0, 0);
    }
    float s1q[4][4], s2q[4][4];
    #pragma unroll
    for (int mr = 0; mr < 4; ++mr)
        #pragma unroll
        for (int reg = 0; reg < 4; ++reg) {
            int rowIdx = lbase + mr * 16 + hi2 * 4 + reg;
            float s1 = 0.f, s2 = 0.f;
            #pragma unroll
            for (int nr = 0; nr < 3; ++nr) {
                int col = wc * 48 + nr * 16 + c16;
                float val = facc[mr][nr][reg] + bf2[col] + bf2f((u16)Ybuf[rowIdx * 200 + col]);
                facc[mr][nr][reg] = val;
                s1 += val; s2 += val * val;
            }
            #pragma unroll
            for (int mS = 1; mS < 16; mS <<= 1) {
                s1 += __shfl_xor(s1, mS, 64);
                s2 += __shfl_xor(s2, mS, 64);
            }
            s1q[mr][reg] = s1; s2q[mr][reg] = s2;
        }
    if (c16 == 0) {
        #pragma unroll
        for (int mr = 0; mr < 4; ++mr)
            #pragma unroll
            for (int reg = 0; reg < 4; ++reg) {
                int rowIdx = lbase + mr * 16 + hi2 * 4 + reg;
                red[0][wc][rowIdx] = s1q[mr][reg];
                red[1][wc][rowIdx] = s2q[mr][reg];
            }
    }
    __syncthreads();
    #pragma unroll
    for (int mr = 0; mr < 4; ++mr)
        #pragma unroll
        for (int reg = 0; reg < 4; ++reg) {
            int rowIdx = lbase + mr * 16 + hi2 * 4 + reg;
            int r = m0 + rowIdx;
            if (r >= M) continue;
            float S1 = red[0][0][rowIdx] + red[0][1][rowIdx] + red[0][2][rowIdx] + red[0][3][rowIdx];
            float S2 = red[1][0][rowIdx] + red[1][1][rowIdx] + red[1][2][rowIdx] + red[1][3][rowIdx];
            float mean = S1 * (1.f / 192.f);
            float var  = S2 * (1.f / 192.f) - mean * mean;
            float inv  = rsqrtf(var + 1e-5f);
            #pragma unroll
            for (int nr = 0; nr < 3; ++nr) {
                int col = wc * 48 + nr * 16 + c16;
                out[(size_t)r * 192 + col] =
                    (facc[mr][nr][reg] - mean) * inv * l2s[col] + l2b[col];
            }
        }
}

// ---------------------------------------------------------------- launcher
extern "C" void kernel_launch(void* const* d_in, const int* in_sizes, int n_in,
                              void* d_out, int out_size, void* d_ws, size_t ws_size,
                              hipStream_t stream) {
    const float* x   = (const float*)d_in[0];
    const float* ef  = (const float*)d_in[1];
    const int*   ei  = (const int*)d_in[2];
    const float* Wq  = (const float*)d_in[3];
    const float* Wk  = (const float*)d_in[4];
    const float* Wv  = (const float*)d_in[5];
    const float* We  = (const float*)d_in[6];
    const float* Wo  = (const float*)d_in[7];
    const float* bo  = (const float*)d_in[8];
    const float* Wg  = (const float*)d_in[9];
    const float* bg  = (const float*)d_in[10];
    const float* l1s = (const float*)d_in[11];
    const float* l1b = (const float*)d_in[12];
    const float* Wf1 = (const float*)d_in[13];
    const float* bf1 = (const float*)d_in[14];
    const float* Wf2 = (const float*)d_in[15];
    const float* bf2 = (const float*)d_in[16];
    const float* l2s = (const float*)d_in[17];
    const float* l2b = (const float*)d_in[18];

    int N = in_sizes[0] / Dm;
    int E = in_sizes[1] / DEe;
    float* out = (float*)d_out;

    char* wp = (char*)d_ws;
    auto alloc = [&](size_t bytes) -> void* {
        void* p = wp;
        wp += (bytes + 255) & ~(size_t)255;
        return p;
    };
    size_t NF = (size_t)N * Dm;
    u16*   xb     = (u16*)alloc(NF * 2);
    u16*   efb    = (u16*)alloc((size_t)E * 96 * 2);
    u16*   qkvb   = (u16*)alloc((size_t)N * 576 * 2);
    u16*   aggb   = (u16*)alloc(NF * 2);
    float* scb    = (float*)alloc((size_t)E * 8 * 4);
    int*   sbuf   = (int*)  alloc((size_t)E * 4);
    int*   degcur = (int*)  alloc((size_t)2 * N * 4);
    int*   offs   = (int*)  alloc((size_t)(N + 1) * 4);
    u16*   Wqkvt  = (u16*)alloc((size_t)576 * 192 * 2);
    u16*   Wot    = (u16*)alloc((size_t)192 * 192 * 2);
    u16*   Wgt    = (u16*)alloc((size_t)192 * 384 * 2);
    u16*   Wf1t   = (u16*)alloc((size_t)384 * 192 * 2);
    u16*   Wf2t   = (u16*)alloc((size_t)192 * 384 * 2);
    u16*   Wet    = (u16*)alloc((size_t)16 * 96 * 2);
    int* deg = degcur;
    int* cur = degcur + N;

    int gm64  = (N + 63) / 64;
    int gm128 = (N + 127) / 128;
    int n4 = N * Dm / 4;
    int nef4 = E * DEe / 4;

    hipMemsetAsync(degcur, 0, (size_t)2 * N * 4, stream);

    long long prepTotal = (long long)E + n4 + nef4 + 370176;
    prepA<<<dim3((unsigned)((prepTotal + 255) / 256)), 256, 0, stream>>>(
        ei, E, x, n4, xb, ef, nef4, efb, Wq, Wk, Wv, Wo, Wg, Wf1, Wf2, We,
        Wqkvt, Wot, Wgt, Wf1t, Wf2t, Wet, deg);

    scan_kernel<<<dim3(1), 1024, 0, stream>>>(deg, N, offs);

    int EB = (E + 255) / 256;
    int QB = gm64 * 3;
    phaseC<<<dim3(EB + QB), 256, 0, stream>>>(EB,
        ei, E, efb, Wet, offs, cur, scb, sbuf,
        xb, N, gm64, Wqkvt, qkvb);

    agg_fused<<<dim3((N + 3) / 4), 256, 0, stream>>>(qkvb, scb, sbuf, offs, N, aggb);

    chain_fused<<<dim3(gm128), 512, 0, stream>>>(aggb, xb, N,
        Wot, bo, Wgt, bg, l1s, l1b, Wf1t, bf1, Wf2t, bf2, l2s, l2b, out);
}

// Round 22
// 264.069 us; speedup vs baseline: 1.1263x; 1.1263x over previous
//
#include <hip/hip_runtime.h>
#include <cstdint>
#include <cstddef>

#define LOG2E 1.4426950408889634f

constexpr int Dm  = 192;
constexpr int DEe = 96;

typedef unsigned short u16;
typedef __attribute__((ext_vector_type(8))) short short8v;
typedef __attribute__((ext_vector_type(4))) float f32x4;
typedef __attribute__((ext_vector_type(4))) uint32_t u32x4;

__device__ __forceinline__ u16 f2bf(float f) {
    uint32_t u = __builtin_bit_cast(uint32_t, f);
    uint32_t r = (u + 0x7FFF + ((u >> 16) & 1)) >> 16;
    return (u16)r;
}
__device__ __forceinline__ float bf2f(u16 h) {
    uint32_t u = ((uint32_t)h) << 16;
    return __builtin_bit_cast(float, u);
}
// packed f32x2 -> bf16x2 (RNE), 1 VALU op for 2 values
__device__ __forceinline__ uint32_t cvtpk_bf16(float lo, float hi) {
    uint32_t r;
    asm("v_cvt_pk_bf16_f32 %0, %1, %2" : "=v"(r) : "v"(lo), "v"(hi));
    return r;
}

// ---------------------------------------------------------------- utilities
__global__ __launch_bounds__(1024) void scan_kernel(const int* __restrict__ deg, int N,
                                                    int* __restrict__ offs) {
    __shared__ int sp[1024];
    int t = threadIdx.x;
    int per = (N + 1023) >> 10;
    int base = t * per;
    int sum = 0;
    for (int i = 0; i < per; ++i) {
        int idx = base + i;
        if (idx < N) sum += deg[idx];
    }
    sp[t] = sum;
    __syncthreads();
    for (int off = 1; off < 1024; off <<= 1) {
        int v = (t >= off) ? sp[t - off] : 0;
        __syncthreads();
        sp[t] += v;
        __syncthreads();
    }
    int run = sp[t] - sum;
    for (int i = 0; i < per; ++i) {
        int idx = base + i;
        if (idx < N) { offs[idx] = run; run += deg[idx]; }
    }
    if (t == 1023) offs[N] = sp[1023];
}

// ---------------- prepA: count_deg | xconv | prep_w | Wet (independent, merged)
__global__ __launch_bounds__(256) void prepA(
    const int* __restrict__ ei, int E,
    const float* __restrict__ x, int n4, u16* __restrict__ xb,
    const float* __restrict__ Wq, const float* __restrict__ Wk,
    const float* __restrict__ Wv, const float* __restrict__ Wo,
    const float* __restrict__ Wg, const float* __restrict__ Wf1,
    const float* __restrict__ Wf2, const float* __restrict__ We,
    u16* __restrict__ Wqkvt, u16* __restrict__ Wot,
    u16* __restrict__ Wgt, u16* __restrict__ Wf1t, u16* __restrict__ Wf2t,
    u16* __restrict__ Wet,
    int* __restrict__ deg)
{
    int i = blockIdx.x * 256 + threadIdx.x;
    if (i < E) {
        atomicAdd(&deg[ei[E + i]], 1);
        return;
    }
    i -= E;
    if (i < n4) {                          // xconv: float4 -> bf16x4
        float4 v = ((const float4*)x)[i];
        uint32_t p0 = cvtpk_bf16(v.x, v.y);
        uint32_t p1 = cvtpk_bf16(v.z, v.w);
        ushort4 o;
        o.x = (u16)(p0 & 0xffff); o.y = (u16)(p0 >> 16);
        o.z = (u16)(p1 & 0xffff); o.w = (u16)(p1 >> 16);
        ((ushort4*)xb)[i] = o;
        return;
    }
    int idx = i - n4;
    if (idx < 110592) {                    // QKV: [576][192]
        int n = idx / 192, k = idx % 192;
        const float* W = n < 192 ? Wq : (n < 384 ? Wk : Wv);
        Wqkvt[idx] = f2bf(W[(size_t)k * 192 + (n % 192)]);
    } else if (idx < 147456) {             // Wo: [192][192]
        int j = idx - 110592;
        int n = j / 192, k = j % 192;
        Wot[j] = f2bf(Wo[(size_t)k * 192 + n]);
    } else if (idx < 221184) {             // Wg: [192][384]
        int j = idx - 147456;
        int n = j / 384, k = j % 384;
        Wgt[j] = f2bf(Wg[(size_t)k * 192 + n]);
    } else if (idx < 294912) {             // Wf1: [384][192]
        int j = idx - 221184;
        int n = j / 192, k = j % 192;
        Wf1t[j] = f2bf(Wf1[(size_t)k * 384 + n]);
    } else if (idx < 368640) {             // Wf2: [192][384]
        int j = idx - 294912;
        int n = j / 384, k = j % 384;
        Wf2t[j] = f2bf(Wf2[(size_t)k * 192 + n]);
    } else if (idx < 370176) {             // Wet: [16][96], log2e-scaled, rows 8..15 = 0
        int j = idx - 368640;
        int n = j / 96, k = j % 96;
        Wet[j] = (n < 8) ? f2bf(We[(size_t)k * 8 + n] * LOG2E) : (u16)0;
    }
}

// ---------------- phaseC: edge MFMA blocks [0,EB) | qkv BM=64 blocks [EB,EB+QB)
// edge role: es = (ef @ We)*log2e via 16x16x32 MFMA (N=8 used of 16, K=96),
// A-fragments loaded straight from global ef (fp32 -> cvt_pk bf16), zero LDS,
// then CSR scatter of es + src.
__global__ __launch_bounds__(256) void phaseC(
    int EB,
    // edge role
    const int* __restrict__ ei, int E,
    const float* __restrict__ ef, const u16* __restrict__ Wet,
    const int* __restrict__ offs, int* __restrict__ cur,
    float* __restrict__ scb, int* __restrict__ sbuf,
    // qkv role
    const u16* __restrict__ xb, int M, int gm64,
    const u16* __restrict__ Wt, u16* __restrict__ qkvb)
{
    int bid = blockIdx.x;
    int tid = threadIdx.x;
    int w = tid >> 6, lane = tid & 63;
    int c16 = lane & 15, hi2 = lane >> 4, kof = hi2 * 8;

    if (bid < EB) {
        // ---------------- edge projection + scatter, 64 edges per wave
        int ebase = bid * 256 + w * 64;
        if (ebase >= E) return;

        // B fragments: Wet[c16][ks*32 + kof .. +8] (rows 8..15 are zero)
        short8v bfr[3];
        #pragma unroll
        for (int ks = 0; ks < 3; ++ks)
            bfr[ks] = *(const short8v*)(Wet + (size_t)c16 * 96 + ks * 32 + kof);

        #pragma unroll 1
        for (int mt = 0; mt < 4; ++mt) {
            int er = ebase + mt * 16 + c16;
            if (er > E - 1) er = E - 1;
            const float* efr = ef + (size_t)er * 96;

            f32x4 acc = (f32x4)(0.f);
            #pragma unroll
            for (int ks = 0; ks < 3; ++ks) {
                float4 fa = *(const float4*)(efr + ks * 32 + kof);
                float4 fb = *(const float4*)(efr + ks * 32 + kof + 4);
                u32x4 pk;
                pk.x = cvtpk_bf16(fa.x, fa.y);
                pk.y = cvtpk_bf16(fa.z, fa.w);
                pk.z = cvtpk_bf16(fb.x, fb.y);
                pk.w = cvtpk_bf16(fb.z, fb.w);
                short8v af = __builtin_bit_cast(short8v, pk);
                acc = __builtin_amdgcn_mfma_f32_16x16x32_bf16(af, bfr[ks], acc, 0, 0, 0);
            }

            // scatter: D row = hi2*4+reg (edge), col = c16 (head, <8 valid)
            int erow0 = ebase + mt * 16 + hi2 * 4;
            int posr[4];
            if (c16 == 0) {
                #pragma unroll
                for (int reg = 0; reg < 4; ++reg) {
                    int e = erow0 + reg;
                    if (e < E) {
                        int dst = ei[E + e];
                        posr[reg] = offs[dst] + atomicAdd(&cur[dst], 1);
                        sbuf[posr[reg]] = ei[e];
                    }
                }
            }
            #pragma unroll
            for (int reg = 0; reg < 4; ++reg) {
                int e = erow0 + reg;
                int p = __shfl(posr[reg], lane & 48, 64);
                if (e < E && c16 < 8)
                    scb[(size_t)p * 8 + c16] = acc[reg];
            }
        }
        return;
    }

    // ---------------- qkv: zero-LDS fragment GEMM, BM=64, 4 waves
    int qb = bid - EB;
    int m0 = (qb % gm64) * 64, n0 = (qb / gm64) * 192;

    int rcm[4];
    #pragma unroll
    for (int mr = 0; mr < 4; ++mr) {
        int r = m0 + mr * 16 + c16;
        rcm[mr] = r < M ? r : M - 1;
    }

    f32x4 acc[4][3];
    #pragma unroll
    for (int mr = 0; mr < 4; ++mr)
        #pragma unroll
        for (int nr = 0; nr < 3; ++nr) acc[mr][nr] = (f32x4)(0.f);

    #pragma unroll 1
    for (int ks = 0; ks < 6; ++ks) {
        short8v af[4], bfr[3];
        #pragma unroll
        for (int mr = 0; mr < 4; ++mr)
            af[mr] = *(const short8v*)(xb + (size_t)rcm[mr] * 192 + ks * 32 + kof);
        #pragma unroll
        for (int nr = 0; nr < 3; ++nr)
            bfr[nr] = *(const short8v*)(Wt + (size_t)(n0 + w * 48 + nr * 16 + c16) * 192 + ks * 32 + kof);
        #pragma unroll
        for (int mr = 0; mr < 4; ++mr)
            #pragma unroll
            for (int nr = 0; nr < 3; ++nr)
                acc[mr][nr] = __builtin_amdgcn_mfma_f32_16x16x32_bf16(
                    af[mr], bfr[nr], acc[mr][nr], 0, 0, 0);
    }

    #pragma unroll
    for (int mr = 0; mr < 4; ++mr)
        #pragma unroll
        for (int nr = 0; nr < 3; ++nr) {
            uint32_t p0 = cvtpk_bf16(acc[mr][nr][0], acc[mr][nr][1]);
            uint32_t p1 = cvtpk_bf16(acc[mr][nr][2], acc[mr][nr][3]);
            int r0 = m0 + mr * 16 + hi2 * 4;
            int col = n0 + w * 48 + nr * 16 + c16;
            if (r0     < M) qkvb[(size_t)(r0    ) * 576 + col] = (u16)(p0 & 0xffff);
            if (r0 + 1 < M) qkvb[(size_t)(r0 + 1) * 576 + col] = (u16)(p0 >> 16);
            if (r0 + 2 < M) qkvb[(size_t)(r0 + 2) * 576 + col] = (u16)(p1 & 0xffff);
            if (r0 + 3 < M) qkvb[(size_t)(r0 + 3) * 576 + col] = (u16)(p1 >> 16);
        }
}

// ---------------------------------------- fused score + softmax + PV per node
// pair-wise, 2-pair-deep software pipeline
__global__ __launch_bounds__(256) void agg_fused(
    const u16* __restrict__ qkv, const float* __restrict__ scb,
    const int* __restrict__ sbuf, const int* __restrict__ offs,
    int N, u16* __restrict__ aggb)
{
    int node = blockIdx.x * 4 + (threadIdx.x >> 6);
    if (node >= N) return;
    int lane = threadIdx.x & 63;
    int h = lane >> 3;
    int di = (3 * lane) >> 1;
    int odd = lane & 1;

    int beg = offs[node], end = offs[node + 1];
    u16* og = aggb + (size_t)node * Dm;
    int b0 = 3 * lane;
    if (beg >= end) {
        og[b0] = 0; og[b0 + 1] = 0; og[b0 + 2] = 0;
        return;
    }

    const uint32_t* qrow = (const uint32_t*)(qkv + (size_t)node * 576);
    uint32_t qd0 = qrow[di], qd1 = qrow[di + 1];
    float q0, q1, q2;
    if (!odd) { q0 = bf2f(qd0 & 0xffff); q1 = bf2f(qd0 >> 16); q2 = bf2f(qd1 & 0xffff); }
    else      { q0 = bf2f(qd0 >> 16);    q1 = bf2f(qd1 & 0xffff); q2 = bf2f(qd1 >> 16); }

    auto clampi = [&](int i) { return i < end ? i : end - 1; };

    float den = 0.f, a0 = 0.f, a1 = 0.f, a2 = 0.f;

    uint32_t ck[2][2], cv[2][2]; float cep[2];
    uint32_t nk[2][2], nv[2][2]; float nep[2];
    int s0, s1;

    {
        int p00 = clampi(beg),     p01 = clampi(beg + 1);
        int p10 = clampi(beg + 2), p11 = clampi(beg + 3);
        int sA = sbuf[p00], sB = sbuf[p01], sC = sbuf[p10], sD = sbuf[p11];
        const uint32_t* r;
        r = (const uint32_t*)(qkv + (size_t)sA * 576 + 192);
        ck[0][0] = r[di]; ck[0][1] = r[di + 1];
        r = (const uint32_t*)(qkv + (size_t)sA * 576 + 384);
        cv[0][0] = r[di]; cv[0][1] = r[di + 1];
        r = (const uint32_t*)(qkv + (size_t)sB * 576 + 192);
        ck[1][0] = r[di]; ck[1][1] = r[di + 1];
        r = (const uint32_t*)(qkv + (size_t)sB * 576 + 384);
        cv[1][0] = r[di]; cv[1][1] = r[di + 1];
        r = (const uint32_t*)(qkv + (size_t)sC * 576 + 192);
        nk[0][0] = r[di]; nk[0][1] = r[di + 1];
        r = (const uint32_t*)(qkv + (size_t)sC * 576 + 384);
        nv[0][0] = r[di]; nv[0][1] = r[di + 1];
        r = (const uint32_t*)(qkv + (size_t)sD * 576 + 192);
        nk[1][0] = r[di]; nk[1][1] = r[di + 1];
        r = (const uint32_t*)(qkv + (size_t)sD * 576 + 384);
        nv[1][0] = r[di]; nv[1][1] = r[di + 1];
        cep[0] = scb[(size_t)p00 * 8 + h]; cep[1] = scb[(size_t)p01 * 8 + h];
        nep[0] = scb[(size_t)p10 * 8 + h]; nep[1] = scb[(size_t)p11 * 8 + h];
        s0 = sbuf[clampi(beg + 4)]; s1 = sbuf[clampi(beg + 5)];
    }

    for (int idx = beg; idx < end; idx += 2) {
        #pragma unroll
        for (int j = 0; j < 2; ++j) {
            float k0, k1, k2, v0, v1, v2;
            uint32_t kd0 = ck[j][0], kd1 = ck[j][1];
            uint32_t vd0 = cv[j][0], vd1 = cv[j][1];
            if (!odd) {
                k0 = bf2f(kd0 & 0xffff); k1 = bf2f(kd0 >> 16); k2 = bf2f(kd1 & 0xffff);
                v0 = bf2f(vd0 & 0xffff); v1 = bf2f(vd0 >> 16); v2 = bf2f(vd1 & 0xffff);
            } else {
                k0 = bf2f(kd0 >> 16); k1 = bf2f(kd1 & 0xffff); k2 = bf2f(kd1 >> 16);
                v0 = bf2f(vd0 >> 16); v1 = bf2f(vd1 & 0xffff); v2 = bf2f(vd1 >> 16);
            }
            float pd = q0 * k0 + q1 * k1 + q2 * k2;
            pd += __shfl_xor(pd, 1, 64);
            pd += __shfl_xor(pd, 2, 64);
            pd += __shfl_xor(pd, 4, 64);
            float p = exp2f(pd * 0.2944885836f + cep[j]);
            if (idx + j < end) {
                den += p;
                a0 += p * v0; a1 += p * v1; a2 += p * v2;
            }
        }
        #pragma unroll
        for (int j = 0; j < 2; ++j) {
            ck[j][0] = nk[j][0]; ck[j][1] = nk[j][1];
            cv[j][0] = nv[j][0]; cv[j][1] = nv[j][1];
            cep[j] = nep[j];
        }
        {
            const uint32_t* r;
            r = (const uint32_t*)(qkv + (size_t)s0 * 576 + 192);
            nk[0][0] = r[di]; nk[0][1] = r[di + 1];
            r = (const uint32_t*)(qkv + (size_t)s0 * 576 + 384);
            nv[0][0] = r[di]; nv[0][1] = r[di + 1];
            r = (const uint32_t*)(qkv + (size_t)s1 * 576 + 192);
            nk[1][0] = r[di]; nk[1][1] = r[di + 1];
            r = (const uint32_t*)(qkv + (size_t)s1 * 576 + 384);
            nv[1][0] = r[di]; nv[1][1] = r[di + 1];
            nep[0] = scb[(size_t)clampi(idx + 4) * 8 + h];
            nep[1] = scb[(size_t)clampi(idx + 5) * 8 + h];
        }
        s0 = sbuf[clampi(idx + 6)]; s1 = sbuf[clampi(idx + 7)];
    }

    float rden = 1.f / (den + 1e-8f);
    og[b0]     = f2bf(a0 * rden);
    og[b0 + 1] = f2bf(a1 * rden);
    og[b0 + 2] = f2bf(a2 * rden);
}

// ---------------------------------------- fused node chain (BM=128, 8 waves)
__global__ __launch_bounds__(512) void chain_fused(
    const u16* __restrict__ aggb, const u16* __restrict__ xb, int M,
    const u16* __restrict__ Wot, const float* __restrict__ bo,
    const u16* __restrict__ Wgt, const float* __restrict__ bg,
    const float* __restrict__ l1s, const float* __restrict__ l1b,
    const u16* __restrict__ Wf1t, const float* __restrict__ bf1,
    const u16* __restrict__ Wf2t, const float* __restrict__ bf2,
    const float* __restrict__ l2s, const float* __restrict__ l2b,
    float* __restrict__ out)
{
    __shared__ __align__(16) short Ybuf[128 * 200];
    __shared__ __align__(16) short Fbuf[128 * 392];
    __shared__ float red[2][4][128];

    int tid = threadIdx.x;
    int m0 = blockIdx.x * 128;
    int w = tid >> 6, lane = tid & 63;
    int wr = w >> 2, wc = w & 3;
    int c16 = lane & 15, hi2 = lane >> 4, kof = hi2 * 8;
    int rbase = m0 + wr * 64;
    int lbase = wr * 64;

    int rcm[4];
    #pragma unroll
    for (int mr = 0; mr < 4; ++mr) {
        int r = rbase + mr * 16 + c16;
        rcm[mr] = r < M ? r : M - 1;
    }

    // ---- stage0: o = agg @ Wo + bo
    f32x4 oacc[4][3];
    #pragma unroll
    for (int mr = 0; mr < 4; ++mr)
        #pragma unroll
        for (int nr = 0; nr < 3; ++nr) oacc[mr][nr] = (f32x4)(0.f);
    #pragma unroll 1
    for (int ks = 0; ks < 6; ++ks) {
        short8v af[4], bfr[3];
        #pragma unroll
        for (int mr = 0; mr < 4; ++mr)
            af[mr] = *(const short8v*)(aggb + (size_t)rcm[mr] * 192 + ks * 32 + kof);
        #pragma unroll
        for (int nr = 0; nr < 3; ++nr)
            bfr[nr] = *(const short8v*)(Wot + (size_t)(wc * 48 + nr * 16 + c16) * 192 + ks * 32 + kof);
        #pragma unroll
        for (int mr = 0; mr < 4; ++mr)
            #pragma unroll
            for (int nr = 0; nr < 3; ++nr)
                oacc[mr][nr] = __builtin_amdgcn_mfma_f32_16x16x32_bf16(
                    af[mr], bfr[nr], oacc[mr][nr], 0, 0, 0);
    }
    #pragma unroll
    for (int nr = 0; nr < 3; ++nr) {
        int col = wc * 48 + nr * 16 + c16;
        float b = bo[col];
        #pragma unroll
        for (int mr = 0; mr < 4; ++mr) {
            #pragma unroll
            for (int reg = 0; reg < 4; ++reg) oacc[mr][nr][reg] += b;
            uint32_t p0 = cvtpk_bf16(oacc[mr][nr][0], oacc[mr][nr][1]);
            uint32_t p1 = cvtpk_bf16(oacc[mr][nr][2], oacc[mr][nr][3]);
            int row0 = lbase + mr * 16 + hi2 * 4;
            Ybuf[(row0    ) * 200 + col] = (short)(p0 & 0xffff);
            Ybuf[(row0 + 1) * 200 + col] = (short)(p0 >> 16);
            Ybuf[(row0 + 2) * 200 + col] = (short)(p1 & 0xffff);
            Ybuf[(row0 + 3) * 200 + col] = (short)(p1 >> 16);
        }
    }
    __syncthreads();

    // ---- stage1: z = [o,x] @ Wg + bg; gate; LN1 -> y
    f32x4 zacc[4][3];
    #pragma unroll
    for (int mr = 0; mr < 4; ++mr)
        #pragma unroll
        for (int nr = 0; nr < 3; ++nr) zacc[mr][nr] = (f32x4)(0.f);
    #pragma unroll 1
    for (int ks = 0; ks < 6; ++ks) {
        short8v af[4], bfr[3];
        #pragma unroll
        for (int mr = 0; mr < 4; ++mr)
            af[mr] = *(const short8v*)&Ybuf[(lbase + mr * 16 + c16) * 200 + ks * 32 + kof];
        #pragma unroll
        for (int nr = 0; nr < 3; ++nr)
            bfr[nr] = *(const short8v*)(Wgt + (size_t)(wc * 48 + nr * 16 + c16) * 384 + ks * 32 + kof);
        #pragma unroll
        for (int mr = 0; mr < 4; ++mr)
            #pragma unroll
            for (int nr = 0; nr < 3; ++nr)
                zacc[mr][nr] = __builtin_amdgcn_mfma_f32_16x16x32_bf16(
                    af[mr], bfr[nr], zacc[mr][nr], 0, 0, 0);
    }
    #pragma unroll 1
    for (int ks = 0; ks < 6; ++ks) {
        short8v af[4], bfr[3];
        #pragma unroll
        for (int mr = 0; mr < 4; ++mr)
            af[mr] = *(const short8v*)(xb + (size_t)rcm[mr] * 192 + ks * 32 + kof);
        #pragma unroll
        for (int nr = 0; nr < 3; ++nr)
            bfr[nr] = *(const short8v*)(Wgt + (size_t)(wc * 48 + nr * 16 + c16) * 384 + 192 + ks * 32 + kof);
        #pragma unroll
        for (int mr = 0; mr < 4; ++mr)
            #pragma unroll
            for (int nr = 0; nr < 3; ++nr)
                zacc[mr][nr] = __builtin_amdgcn_mfma_f32_16x16x32_bf16(
                    af[mr], bfr[nr], zacc[mr][nr], 0, 0, 0);
    }
    float s1p[4][4], s2p[4][4];
    #pragma unroll
    for (int mr = 0; mr < 4; ++mr)
        #pragma unroll
        for (int reg = 0; reg < 4; ++reg) {
            int gr = rbase + mr * 16 + hi2 * 4 + reg;
            int rcR = gr < M ? gr : M - 1;
            float s1 = 0.f, s2 = 0.f;
            #pragma unroll
            for (int nr = 0; nr < 3; ++nr) {
                int col = wc * 48 + nr * 16 + c16;
                float z = zacc[mr][nr][reg] + bg[col];
                float g = 1.f / (1.f + expf(-z));
                float xv = bf2f(xb[(size_t)rcR * 192 + col]);
                float val = g * oacc[mr][nr][reg] + (1.f - g) * xv;
                zacc[mr][nr][reg] = val;
                s1 += val; s2 += val * val;
            }
            #pragma unroll
            for (int mS = 1; mS < 16; mS <<= 1) {
                s1 += __shfl_xor(s1, mS, 64);
                s2 += __shfl_xor(s2, mS, 64);
            }
            s1p[mr][reg] = s1; s2p[mr][reg] = s2;
        }
    if (c16 == 0) {
        #pragma unroll
        for (int mr = 0; mr < 4; ++mr)
            #pragma unroll
            for (int reg = 0; reg < 4; ++reg) {
                int rowIdx = lbase + mr * 16 + hi2 * 4 + reg;
                red[0][wc][rowIdx] = s1p[mr][reg];
                red[1][wc][rowIdx] = s2p[mr][reg];
            }
    }
    __syncthreads();
    #pragma unroll
    for (int mr = 0; mr < 4; ++mr)
        #pragma unroll
        for (int reg = 0; reg < 4; ++reg) {
            int rowIdx = lbase + mr * 16 + hi2 * 4 + reg;
            float S1 = red[0][0][rowIdx] + red[0][1][rowIdx] + red[0][2][rowIdx] + red[0][3][rowIdx];
            float S2 = red[1][0][rowIdx] + red[1][1][rowIdx] + red[1][2][rowIdx] + red[1][3][rowIdx];
            float mean = S1 * (1.f / 192.f);
            float var  = S2 * (1.f / 192.f) - mean * mean;
            float inv  = rsqrtf(var + 1e-5f);
            #pragma unroll
            for (int nr = 0; nr < 3; ++nr) {
                int col = wc * 48 + nr * 16 + c16;
                float yv = (zacc[mr][nr][reg] - mean) * inv * l1s[col] + l1b[col];
                Ybuf[rowIdx * 200 + col] = (short)f2bf(yv);
            }
        }
    __syncthreads();

    // ---- stage2: t = silu(y @ Wf1 + bf1)
    f32x4 tacc[4][6];
    #pragma unroll
    for (int mr = 0; mr < 4; ++mr)
        #pragma unroll
        for (int nr = 0; nr < 6; ++nr) tacc[mr][nr] = (f32x4)(0.f);
    #pragma unroll 1
    for (int ks = 0; ks < 6; ++ks) {
        short8v af[4], bfr[6];
        #pragma unroll
        for (int mr = 0; mr < 4; ++mr)
            af[mr] = *(const short8v*)&Ybuf[(lbase + mr * 16 + c16) * 200 + ks * 32 + kof];
        #pragma unroll
        for (int nr = 0; nr < 6; ++nr)
            bfr[nr] = *(const short8v*)(Wf1t + (size_t)(wc * 96 + nr * 16 + c16) * 192 + ks * 32 + kof);
        #pragma unroll
        for (int mr = 0; mr < 4; ++mr)
            #pragma unroll
            for (int nr = 0; nr < 6; ++nr)
                tacc[mr][nr] = __builtin_amdgcn_mfma_f32_16x16x32_bf16(
                    af[mr], bfr[nr], tacc[mr][nr], 0, 0, 0);
    }
    #pragma unroll
    for (int nr = 0; nr < 6; ++nr) {
        int col = wc * 96 + nr * 16 + c16;
        float b = bf1[col];
        #pragma unroll
        for (int mr = 0; mr < 4; ++mr) {
            float t0[4];
            #pragma unroll
            for (int reg = 0; reg < 4; ++reg) {
                float z = tacc[mr][nr][reg] + b;
                t0[reg] = z / (1.f + expf(-z));
            }
            uint32_t p0 = cvtpk_bf16(t0[0], t0[1]);
            uint32_t p1 = cvtpk_bf16(t0[2], t0[3]);
            int row0 = lbase + mr * 16 + hi2 * 4;
            Fbuf[(row0    ) * 392 + col] = (short)(p0 & 0xffff);
            Fbuf[(row0 + 1) * 392 + col] = (short)(p0 >> 16);
            Fbuf[(row0 + 2) * 392 + col] = (short)(p1 & 0xffff);
            Fbuf[(row0 + 3) * 392 + col] = (short)(p1 >> 16);
        }
    }
    __syncthreads();

    // ---- stage3: out = LN2(y + t @ Wf2 + bf2)
    f32x4 facc[4][3];
    #pragma unroll
    for (int mr = 0; mr < 4; ++mr)
        #pragma unroll
        for (int nr = 0; nr < 3; ++nr) facc[mr][nr] = (f32x4)(0.f);
    #pragma unroll 1
    for (int ks = 0; ks < 12; ++ks) {
        short8v af[4], bfr[3];
        #pragma unroll
        for (int mr = 0; mr < 4; ++mr)
            af[mr] = *(const short8v*)&Fbuf[(lbase + mr * 16 + c16) * 392 + ks * 32 + kof];
        #pragma unroll
        for (int nr = 0; nr < 3; ++nr)
            bfr[nr] = *(const short8v*)(Wf2t + (size_t)(wc * 48 + nr * 16 + c16) * 384 + ks * 32 + kof);
        #pragma unroll
        for (int mr = 0; mr < 4; ++mr)
            #pragma unroll
            for (int nr = 0; nr < 3; ++nr)
                facc[mr][nr] = __builtin_amdgcn_mfma_f32_16x16x32_bf16(
                    af[mr], bfr[nr], facc[mr][nr], 0, 0, 0);
    }
    float s1q[4][4], s2q[4][4];
    #pragma unroll
    for (int mr = 0; mr < 4; ++mr)
        #pragma unroll
        for (int reg = 0; reg < 4; ++reg) {
            int rowIdx = lbase + mr * 16 + hi2 * 4 + reg;
            float s1 = 0.f, s2 = 0.f;
            #pragma unroll
            for (int nr = 0; nr < 3; ++nr) {
                int col = wc * 48 + nr * 16 + c16;
                float val = facc[mr][nr][reg] + bf2[col] + bf2f((u16)Ybuf[rowIdx * 200 + col]);
                facc[mr][nr][reg] = val;
                s1 += val; s2 += val * val;
            }
            #pragma unroll
            for (int mS = 1; mS < 16; mS <<= 1) {
                s1 += __shfl_xor(s1, mS, 64);
                s2 += __shfl_xor(s2, mS, 64);
            }
            s1q[mr][reg] = s1; s2q[mr][reg] = s2;
        }
    if (c16 == 0) {
        #pragma unroll
        for (int mr = 0; mr < 4; ++mr)
            #pragma unroll
            for (int reg = 0; reg < 4; ++reg) {
                int rowIdx = lbase + mr * 16 + hi2 * 4 + reg;
                red[0][wc][rowIdx] = s1q[mr][reg];
                red[1][wc][rowIdx] = s2q[mr][reg];
            }
    }
    __syncthreads();
    #pragma unroll
    for (int mr = 0; mr < 4; ++mr)
        #pragma unroll
        for (int reg = 0; reg < 4; ++reg) {
            int rowIdx = lbase + mr * 16 + hi2 * 4 + reg;
            int r = m0 + rowIdx;
            if (r >= M) continue;
            float S1 = red[0][0][rowIdx] + red[0][1][rowIdx] + red[0][2][rowIdx] + red[0][3][rowIdx];
            float S2 = red[1][0][rowIdx] + red[1][1][rowIdx] + red[1][2][rowIdx] + red[1][3][rowIdx];
            float mean = S1 * (1.f / 192.f);
            float var  = S2 * (1.f / 192.f) - mean * mean;
            float inv  = rsqrtf(var + 1e-5f);
            #pragma unroll
            for (int nr = 0; nr < 3; ++nr) {
                int col = wc * 48 + nr * 16 + c16;
                out[(size_t)r * 192 + col] =
                    (facc[mr][nr][reg] - mean) * inv * l2s[col] + l2b[col];
            }
        }
}

// ---------------------------------------------------------------- launcher
extern "C" void kernel_launch(void* const* d_in, const int* in_sizes, int n_in,
                              void* d_out, int out_size, void* d_ws, size_t ws_size,
                              hipStream_t stream) {
    const float* x   = (const float*)d_in[0];
    const float* ef  = (const float*)d_in[1];
    const int*   ei  = (const int*)d_in[2];
    const float* Wq  = (const float*)d_in[3];
    const float* Wk  = (const float*)d_in[4];
    const float* Wv  = (const float*)d_in[5];
    const float* We  = (const float*)d_in[6];
    const float* Wo  = (const float*)d_in[7];
    const float* bo  = (const float*)d_in[8];
    const float* Wg  = (const float*)d_in[9];
    const float* bg  = (const float*)d_in[10];
    const float* l1s = (const float*)d_in[11];
    const float* l1b = (const float*)d_in[12];
    const float* Wf1 = (const float*)d_in[13];
    const float* bf1 = (const float*)d_in[14];
    const float* Wf2 = (const float*)d_in[15];
    const float* bf2 = (const float*)d_in[16];
    const float* l2s = (const float*)d_in[17];
    const float* l2b = (const float*)d_in[18];

    int N = in_sizes[0] / Dm;
    int E = in_sizes[1] / DEe;
    float* out = (float*)d_out;

    char* wp = (char*)d_ws;
    auto alloc = [&](size_t bytes) -> void* {
        void* p = wp;
        wp += (bytes + 255) & ~(size_t)255;
        return p;
    };
    size_t NF = (size_t)N * Dm;
    u16*   xb     = (u16*)alloc(NF * 2);
    u16*   qkvb   = (u16*)alloc((size_t)N * 576 * 2);
    u16*   aggb   = (u16*)alloc(NF * 2);
    float* scb    = (float*)alloc((size_t)E * 8 * 4);
    int*   sbuf   = (int*)  alloc((size_t)E * 4);
    int*   degcur = (int*)  alloc((size_t)2 * N * 4);
    int*   offs   = (int*)  alloc((size_t)(N + 1) * 4);
    u16*   Wqkvt  = (u16*)alloc((size_t)576 * 192 * 2);
    u16*   Wot    = (u16*)alloc((size_t)192 * 192 * 2);
    u16*   Wgt    = (u16*)alloc((size_t)192 * 384 * 2);
    u16*   Wf1t   = (u16*)alloc((size_t)384 * 192 * 2);
    u16*   Wf2t   = (u16*)alloc((size_t)192 * 384 * 2);
    u16*   Wet    = (u16*)alloc((size_t)16 * 96 * 2);
    int* deg = degcur;
    int* cur = degcur + N;

    int gm64  = (N + 63) / 64;
    int gm128 = (N + 127) / 128;
    int n4 = N * Dm / 4;

    hipMemsetAsync(degcur, 0, (size_t)2 * N * 4, stream);

    int prepTotal = E + n4 + 370176;
    prepA<<<dim3((prepTotal + 255) / 256), 256, 0, stream>>>(
        ei, E, x, n4, xb, Wq, Wk, Wv, Wo, Wg, Wf1, Wf2, We,
        Wqkvt, Wot, Wgt, Wf1t, Wf2t, Wet, deg);

    scan_kernel<<<dim3(1), 1024, 0, stream>>>(deg, N, offs);

    int EB = (E + 255) / 256;
    int QB = gm64 * 3;
    phaseC<<<dim3(EB + QB), 256, 0, stream>>>(EB,
        ei, E, ef, Wet, offs, cur, scb, sbuf,
        xb, N, gm64, Wqkvt, qkvb);

    agg_fused<<<dim3((N + 3) / 4), 256, 0, stream>>>(qkvb, scb, sbuf, offs, N, aggb);

    chain_fused<<<dim3(gm128), 512, 0, stream>>>(aggb, xb, N,
        Wot, bo, Wgt, bg, l1s, l1b, Wf1t, bf1, Wf2t, bf2, l2s, l2b, out);
}